// Round 3
// baseline (93.510 us; speedup 1.0000x reference)
//
#include <hip/hip_runtime.h>

#define BATCH    8192
#define NF       39      // num_fields
#define ED       64      // embed dim
#define RANK     32
#define NFRAG    15      // 5 l-slices x 3 k-chunks

typedef _Float16 half8  __attribute__((ext_vector_type(8)));
typedef float    f32x16 __attribute__((ext_vector_type(16)));

// ---- prep: build the 15 W A-fragments in per-lane MFMA layout (proven path) ----
// wsW[(l*3+kc)*64 + lane] = half8 of W row j=lane&31, k = kc*16 + (lane>>5)*8 + e.
__global__ void prep_w(const float* __restrict__ W0,
                       const float* __restrict__ W1,
                       half8* __restrict__ wsW) {
    int d = blockIdx.x * 256 + threadIdx.x;
    if (d >= NFRAG * 64) return;
    int fid  = d >> 6;
    int lane = d & 63;
    int l = fid / 3, kc = fid % 3;
    int j = lane & 31, kh = lane >> 5;
    const float* base = (l < 2) ? (W0 + (l * RANK + j) * NF)
                                : (W1 + ((l - 2) * RANK + j) * NF);
    half8 h;
#pragma unroll
    for (int e = 0; e < 8; ++e) {
        int k = kc * 16 + kh * 8 + e;
        h[e] = (k < NF) ? (_Float16)base[k] : (_Float16)0.0f;
    }
    wsW[d] = h;
}

union H8U { half8 h; unsigned int u[4]; };

// direct-to-LDS 16B copy (no VGPR round-trip)
__device__ __forceinline__ void glds16(const void* g, void* l) {
    __builtin_amdgcn_global_load_lds(
        (const __attribute__((address_space(1))) unsigned int*)g,
        (__attribute__((address_space(3))) unsigned int*)l, 16, 0, 0);
}

// One wave = one sample. A-frags from LDS (staged via global_load_lds).
// x row via s_load (SGPRs) -> gathers issue off scalar bases, no readlane chain.
// B-frags built in registers via v_permlane32_swap (proven in R2).
// Zero-init trick: one zeroed f32x16 'z' feeds every accumulator's first MFMA
// as the C operand (D != C so z stays zero) -> kills ~144 v_mov acc inits.
// launch_bounds (256,3): 170-VGPR cap -> no spill risk (16->12 waves/CU
// measured worth <=2%, spills would cost far more).
__global__ __launch_bounds__(256, 3) void tfm_kernel(
    const int*   __restrict__ x,        // (B, NF)
    const float* __restrict__ embed,    // (100000, ED)
    const float* __restrict__ linw,     // (100000, 1)
    const float* __restrict__ lbias,    // (1,)
    const half8* __restrict__ wsW,      // [NFRAG][64]
    float*       __restrict__ out)      // (B,)
{
    __shared__ __align__(16) _Float16 Ws[NFRAG * 64 * 8];   // 15360 B total LDS

    const int t    = threadIdx.x;
    const int lane = t & 63;
    const int w    = t >> 6;
    const int s    = blockIdx.x * 4 + w;     // one sample per wave

    // ---- x row -> SGPRs (uniform per wave): short SMEM wait, no readlanes ----
    const int srow = __builtin_amdgcn_readfirstlane(s);
    const int* __restrict__ xrow = x + srow * NF;
    int xi[NF];
#pragma unroll
    for (int k = 0; k < NF; ++k) xi[k] = xrow[k];          // s_load_dwordx*

    // independent vector chain for the linear term (issued in parallel)
    const int xi_v = (lane < NF) ? x[s * NF + lane] : 0;

    // ---- 39 coalesced 256 B row gathers, SGPR base + lane*4 ----
    float r[NF];
#pragma unroll
    for (int k = 0; k < NF; ++k)
        r[k] = embed[(size_t)xi[k] * ED + lane];

    // ---- stage Ws via global_load_lds: no VGPR temps in the gather peak ----
    // chunk c (1024 B = 64 lanes x 16 B): wave w takes c = w, w+4, w+8, w+12.
    // Linear: LDS byte (c*64+lane)*16 <- wsW[c*64+lane]. Matches exactly.
#pragma unroll
    for (int i = 0; i < 4; ++i) {
        int c = w + i * 4;
        if (c < NFRAG)
            glds16(&wsW[c * 64 + lane], &Ws[(c * 64 + lane) * 8]);
    }

    // linear-term gather last: 64 scattered lines, don't delay the row gathers
    const float lv   = (lane < NF) ? linw[xi_v] : 0.0f;
    const float bias = lbias[0];

    // ---- B-frags in registers: pack f16 (RNE) then permlane32_swap ----
    //   A' lane l = l<32 ? own pkA (col l, kh=0)  : partner pkB (col l-32, kh=1) == bf_tile0
    //   B' lane l = l<32 ? partner pkA (col l+32) : own pkB (col l)              == bf_tile1
    // kc=2 tail (k=39..47) = explicit zeros (A-side Ws is zero there too).
    half8 bf0[3], bf1[3];
#pragma unroll
    for (int kc = 0; kc < 3; ++kc) {
        H8U A, B;
#pragma unroll
        for (int e = 0; e < 8; ++e) {
            int kA = kc * 16 + e;
            int kB = kc * 16 + 8 + e;
            A.h[e] = (kA < NF) ? (_Float16)r[kA] : (_Float16)0.0f;
            B.h[e] = (kB < NF) ? (_Float16)r[kB] : (_Float16)0.0f;
        }
#pragma unroll
        for (int q = 0; q < 4; ++q)
            asm volatile("v_permlane32_swap_b32 %0, %1"
                         : "+v"(A.u[q]), "+v"(B.u[q]));
        bf0[kc] = A.h;
        bf1[kc] = B.h;
    }

    __syncthreads();   // Ws visible to all waves (vmcnt(0) drain covers glds)

    const half8* Wf = (const half8*)Ws;
    float ssum = lv;

    f32x16 z;
#pragma unroll
    for (int e = 0; e < 16; ++e) z[e] = 0.0f;

    // Per tile: phase W0 (2 acc, fold product), phase W1 (3 acc, fold triple).
    // First kc of each acc consumes z as C-in (no per-acc zero-init movs).
    // Tree folds: no fast-math, serial ssum+= would be a 16-deep dependent chain.
#define TILE_BODY(BF)                                                          \
    {                                                                          \
        f32x16 a0 = __builtin_amdgcn_mfma_f32_32x32x16_f16(                    \
                        Wf[(0 * 3 + 0) * 64 + lane], BF[0], z, 0, 0, 0);       \
        f32x16 a1 = __builtin_amdgcn_mfma_f32_32x32x16_f16(                    \
                        Wf[(1 * 3 + 0) * 64 + lane], BF[0], z, 0, 0, 0);       \
        _Pragma("unroll")                                                      \
        for (int kc = 1; kc < 3; ++kc) {                                       \
            a0 = __builtin_amdgcn_mfma_f32_32x32x16_f16(                       \
                     Wf[(0 * 3 + kc) * 64 + lane], BF[kc], a0, 0, 0, 0);       \
            a1 = __builtin_amdgcn_mfma_f32_32x32x16_f16(                       \
                     Wf[(1 * 3 + kc) * 64 + lane], BF[kc], a1, 0, 0, 0);       \
        }                                                                      \
        float p0 = 0.f, p1 = 0.f, p2 = 0.f, p3 = 0.f;                          \
        _Pragma("unroll")                                                      \
        for (int e = 0; e < 4; ++e) {                                          \
            p0 += a0[e]      * a1[e];                                          \
            p1 += a0[4 + e]  * a1[4 + e];                                      \
            p2 += a0[8 + e]  * a1[8 + e];                                      \
            p3 += a0[12 + e] * a1[12 + e];                                     \
        }                                                                      \
        ssum += (p0 + p1) + (p2 + p3);                                         \
        f32x16 c0 = __builtin_amdgcn_mfma_f32_32x32x16_f16(                    \
                        Wf[(2 * 3 + 0) * 64 + lane], BF[0], z, 0, 0, 0);       \
        f32x16 c1 = __builtin_amdgcn_mfma_f32_32x32x16_f16(                    \
                        Wf[(3 * 3 + 0) * 64 + lane], BF[0], z, 0, 0, 0);       \
        f32x16 c2 = __builtin_amdgcn_mfma_f32_32x32x16_f16(                    \
                        Wf[(4 * 3 + 0) * 64 + lane], BF[0], z, 0, 0, 0);       \
        _Pragma("unroll")                                                      \
        for (int kc = 1; kc < 3; ++kc) {                                       \
            c0 = __builtin_amdgcn_mfma_f32_32x32x16_f16(                       \
                     Wf[(2 * 3 + kc) * 64 + lane], BF[kc], c0, 0, 0, 0);       \
            c1 = __builtin_amdgcn_mfma_f32_32x32x16_f16(                       \
                     Wf[(3 * 3 + kc) * 64 + lane], BF[kc], c1, 0, 0, 0);       \
            c2 = __builtin_amdgcn_mfma_f32_32x32x16_f16(                       \
                     Wf[(4 * 3 + kc) * 64 + lane], BF[kc], c2, 0, 0, 0);       \
        }                                                                      \
        float q0 = 0.f, q1 = 0.f, q2 = 0.f, q3 = 0.f;                          \
        _Pragma("unroll")                                                      \
        for (int e = 0; e < 4; ++e) {                                          \
            q0 += c0[e]      * c1[e]      * c2[e];                             \
            q1 += c0[4 + e]  * c1[4 + e]  * c2[4 + e];                         \
            q2 += c0[8 + e]  * c1[8 + e]  * c2[8 + e];                         \
            q3 += c0[12 + e] * c1[12 + e] * c2[12 + e];                        \
        }                                                                      \
        ssum += (q0 + q1) + (q2 + q3);                                         \
    }

    TILE_BODY(bf0)   // columns 0..31
    TILE_BODY(bf1)   // columns 32..63
#undef TILE_BODY

    // ---- 64-lane reduce, lane 0 writes ----
#pragma unroll
    for (int off = 32; off > 0; off >>= 1) ssum += __shfl_down(ssum, off, 64);
    if (lane == 0) out[s] = ssum + bias;
}

extern "C" void kernel_launch(void* const* d_in, const int* in_sizes, int n_in,
                              void* d_out, int out_size, void* d_ws, size_t ws_size,
                              hipStream_t stream) {
    const int*   x     = (const int*)  d_in[0];
    const float* embed = (const float*)d_in[1];
    const float* linw  = (const float*)d_in[2];
    const float* lbias = (const float*)d_in[3];
    const float* W0    = (const float*)d_in[4];
    const float* W1    = (const float*)d_in[5];
    float*       out   = (float*)d_out;
    half8*       wsW   = (half8*)d_ws;          // 15*64*16 B = 15360 B

    prep_w<<<(NFRAG * 64 + 255) / 256, 256, 0, stream>>>(W0, W1, wsW);
    // 2048 blocks x 4 waves x 1 sample = 8192
    tfm_kernel<<<BATCH / 4, 256, 0, stream>>>(x, embed, linw, lbias, wsW, out);
}